// Round 1
// baseline (606.469 us; speedup 1.0000x reference)
//
#include <hip/hip_runtime.h>
#include <hip/hip_bf16.h>

typedef __bf16 bf16;
typedef __bf16 bf16x8 __attribute__((ext_vector_type(8)));
typedef __bf16 bf16x4 __attribute__((ext_vector_type(4)));
typedef float f32x4 __attribute__((ext_vector_type(4)));

#define MFMA16(a, b, c) __builtin_amdgcn_mfma_f32_16x16x32_bf16(a, b, c, 0, 0, 0)

// ---------------- convert x (fp32 -> bf16) ----------------
__global__ void k_cvt(const float* __restrict__ in, bf16* __restrict__ out, int n4) {
    int i = blockIdx.x * 256 + threadIdx.x;
    if (i < n4) {
        float4 v = ((const float4*)in)[i];
        bf16x4 o = { (bf16)v.x, (bf16)v.y, (bf16)v.z, (bf16)v.w };
        *(bf16x4*)(out + (long)i * 4) = o;
    }
}

// ---------------- transpose fp32 [R][C] -> bf16 [C][R] ----------------
__global__ void k_transpose(const float* __restrict__ in, bf16* __restrict__ out, int R, int C) {
    __shared__ float t[32][33];
    int c0 = blockIdx.x * 32, r0 = blockIdx.y * 32;
    int tx = threadIdx.x, ty = threadIdx.y; // 32 x 8
    for (int j = 0; j < 4; ++j)
        t[ty + 8 * j][tx] = in[(long)(r0 + ty + 8 * j) * C + c0 + tx];
    __syncthreads();
    for (int j = 0; j < 4; ++j)
        out[(long)(c0 + ty + 8 * j) * R + r0 + tx] = (bf16)t[tx][ty + 8 * j];
}

// ---------------- GEMM C = A * B^T (A:[M][K] bf16, BT:[N][K] bf16) ----------------
// MODE 0: QKV epilogue (bias, scale Q by 0.125, scatter to Q[B,H,S,D], K[B,H,S,D], Vt[B,H,D,S])
// MODE 1: out epilogue (bias, fp32 store row-major [M][N])
template <int MODE>
__launch_bounds__(256)
__global__ void k_gemm_bt(const bf16* __restrict__ A, const bf16* __restrict__ BT, int K,
                          const float* __restrict__ bias,
                          bf16* __restrict__ Qg, bf16* __restrict__ Kg, bf16* __restrict__ Vt,
                          float* __restrict__ Out) {
    __shared__ bf16 As[128][40];
    __shared__ bf16 Bs[128][40];
    int tid = threadIdx.x;
    int w = tid >> 6, lane = tid & 63;
    int m0 = blockIdx.y * 128, n0 = blockIdx.x * 128;
    int wm = (w >> 1) * 64, wn = (w & 1) * 64;
    f32x4 acc[4][4] = {};
    int srow = tid >> 1, scol = (tid & 1) * 16;
    const bf16* ap = A + (long)(m0 + srow) * K + scol;
    const bf16* bp = BT + (long)(n0 + srow) * K + scol;
    int la = lane & 15, g8 = (lane >> 4) * 8;

    for (int kk = 0; kk < K; kk += 32) {
        bf16x8 av0 = *(const bf16x8*)(ap + kk);
        bf16x8 av1 = *(const bf16x8*)(ap + kk + 8);
        bf16x8 bv0 = *(const bf16x8*)(bp + kk);
        bf16x8 bv1 = *(const bf16x8*)(bp + kk + 8);
        *(bf16x8*)&As[srow][scol] = av0;
        *(bf16x8*)&As[srow][scol + 8] = av1;
        *(bf16x8*)&Bs[srow][scol] = bv0;
        *(bf16x8*)&Bs[srow][scol + 8] = bv1;
        __syncthreads();
        bf16x8 af[4], bfv[4];
        for (int i = 0; i < 4; ++i) af[i] = *(const bf16x8*)&As[wm + i * 16 + la][g8];
        for (int i = 0; i < 4; ++i) bfv[i] = *(const bf16x8*)&Bs[wn + i * 16 + la][g8];
        for (int i = 0; i < 4; ++i)
            for (int j = 0; j < 4; ++j)
                acc[i][j] = MFMA16(af[i], bfv[j], acc[i][j]);
        __syncthreads();
    }

    for (int j = 0; j < 4; ++j) {
        int n = n0 + wn + j * 16 + la;
        float bb = bias[n];
        if (MODE == 0) {
            int which = n >> 10, e = n & 1023, h = e >> 6, d = e & 63;
            for (int i = 0; i < 4; ++i) {
                int mbase = m0 + wm + i * 16 + (lane >> 4) * 4;
                for (int r = 0; r < 4; ++r) {
                    int m = mbase + r;
                    float v = acc[i][j][r] + bb;
                    int b = m >> 12, s = m & 4095;
                    long bhh = (long)(b * 16 + h);
                    if (which == 0)      Qg[(bhh * 4096 + s) * 64 + d] = (bf16)(v * 0.125f);
                    else if (which == 1) Kg[(bhh * 4096 + s) * 64 + d] = (bf16)v;
                    else                 Vt[(bhh * 64 + d) * 4096 + s] = (bf16)v;
                }
            }
        } else {
            for (int i = 0; i < 4; ++i) {
                int mbase = m0 + wm + i * 16 + (lane >> 4) * 4;
                for (int r = 0; r < 4; ++r)
                    Out[(long)(mbase + r) * 1024 + n] = acc[i][j][r] + bb;
            }
        }
    }
}

// ---------------- flash attention ----------------
// Q[B*H][S][64] (pre-scaled by 1/8), K[B*H][S][64], Vt[B*H][64][S] all bf16.
// Output Ob: [B][S][H*64] bf16. Block: 4 waves x 16 q-rows = 64 q rows. KV tile = 64.
__launch_bounds__(256)
__global__ void k_attn(const bf16* __restrict__ Qg, const bf16* __restrict__ Kg,
                       const bf16* __restrict__ Vt, bf16* __restrict__ Ob) {
    __shared__ bf16 Kl[64][72];
    __shared__ bf16 Vl[64][72];
    __shared__ bf16 Pl[4][16][72];
    int tid = threadIdx.x, w = tid >> 6, lane = tid & 63;
    int bh = blockIdx.x >> 6;
    int qt = blockIdx.x & 63;
    const bf16* Qp = Qg + ((long)bh * 4096 + qt * 64 + w * 16) * 64;
    const bf16* Kp = Kg + (long)bh * 4096 * 64;
    const bf16* Vp = Vt + (long)bh * 64 * 4096;
    int la = lane & 15, g = lane >> 4, g8 = g * 8;

    bf16x8 qf0 = *(const bf16x8*)(Qp + la * 64 + g8);
    bf16x8 qf1 = *(const bf16x8*)(Qp + la * 64 + 32 + g8);
    f32x4 o[4] = {};
    float mrun[4] = {-1e30f, -1e30f, -1e30f, -1e30f};
    float lrun[4] = {0.f, 0.f, 0.f, 0.f};

    for (int kv = 0; kv < 4096; kv += 64) {
        for (int it = 0; it < 2; ++it) {
            int ch = tid + it * 256;           // 0..511 chunks of 8 bf16
            int row = ch >> 3, c8 = (ch & 7) * 8;
            *(bf16x8*)&Kl[row][c8] = *(const bf16x8*)(Kp + (long)(kv + row) * 64 + c8);
            *(bf16x8*)&Vl[row][c8] = *(const bf16x8*)(Vp + (long)row * 4096 + kv + c8);
        }
        __syncthreads();

        f32x4 s[4] = {};
        for (int n = 0; n < 4; ++n) {
            bf16x8 k0 = *(const bf16x8*)&Kl[n * 16 + la][g8];
            bf16x8 k1 = *(const bf16x8*)&Kl[n * 16 + la][32 + g8];
            s[n] = MFMA16(qf0, k0, s[n]);
            s[n] = MFMA16(qf1, k1, s[n]);
        }

        float resc[4];
        for (int r = 0; r < 4; ++r) {
            float v = fmaxf(fmaxf(s[0][r], s[1][r]), fmaxf(s[2][r], s[3][r]));
            v = fmaxf(v, __shfl_xor(v, 1));
            v = fmaxf(v, __shfl_xor(v, 2));
            v = fmaxf(v, __shfl_xor(v, 4));
            v = fmaxf(v, __shfl_xor(v, 8));
            float nm = fmaxf(mrun[r], v);
            resc[r] = __builtin_exp2f((mrun[r] - nm) * 1.44269504f);
            mrun[r] = nm;
        }
        float ps[4] = {0.f, 0.f, 0.f, 0.f};
        for (int n = 0; n < 4; ++n)
            for (int r = 0; r < 4; ++r) {
                float p = __builtin_exp2f((s[n][r] - mrun[r]) * 1.44269504f);
                s[n][r] = p;
                ps[r] += p;
            }
        for (int r = 0; r < 4; ++r) {
            float v = ps[r];
            v += __shfl_xor(v, 1);
            v += __shfl_xor(v, 2);
            v += __shfl_xor(v, 4);
            v += __shfl_xor(v, 8);
            lrun[r] = lrun[r] * resc[r] + v;
            for (int d = 0; d < 4; ++d) o[d][r] *= resc[r];
        }
        for (int n = 0; n < 4; ++n)
            for (int r = 0; r < 4; ++r)
                Pl[w][g * 4 + r][n * 16 + la] = (bf16)s[n][r];

        bf16x8 pf0 = *(const bf16x8*)&Pl[w][la][g8];
        bf16x8 pf1 = *(const bf16x8*)&Pl[w][la][32 + g8];
        for (int d = 0; d < 4; ++d) {
            bf16x8 v0 = *(const bf16x8*)&Vl[d * 16 + la][g8];
            bf16x8 v1 = *(const bf16x8*)&Vl[d * 16 + la][32 + g8];
            o[d] = MFMA16(pf0, v0, o[d]);
            o[d] = MFMA16(pf1, v1, o[d]);
        }
        __syncthreads();
    }

    int b = bh >> 4, h = bh & 15;
    long srow = (long)qt * 64 + w * 16 + g * 4;
    for (int d = 0; d < 4; ++d)
        for (int r = 0; r < 4; ++r) {
            float v = o[d][r] / lrun[r];
            Ob[((long)b * 4096 + srow + r) * 1024 + h * 64 + d * 16 + la] = (bf16)v;
        }
}

extern "C" void kernel_launch(void* const* d_in, const int* in_sizes, int n_in,
                              void* d_out, int out_size, void* d_ws, size_t ws_size,
                              hipStream_t stream) {
    const float* x    = (const float*)d_in[0];
    const float* Wqkv = (const float*)d_in[1];
    const float* bqkv = (const float*)d_in[2];
    const float* Wout = (const float*)d_in[3];
    const float* bout = (const float*)d_in[4];
    float* out = (float*)d_out;
    char* ws = (char*)d_ws;

    bf16* xb    = (bf16*)(ws);                 // 8192*1024*2      = 16777216
    bf16* WqkvT = (bf16*)(ws + 16777216);      // 3072*1024*2      =  6291456
    bf16* WoutT = (bf16*)(ws + 23068672);      // 1024*1024*2      =  2097152
    bf16* Qg    = (bf16*)(ws + 25165824);      // 32*4096*64*2     = 16777216
    bf16* Kg    = (bf16*)(ws + 41943040);
    bf16* Vt    = (bf16*)(ws + 58720256);
    bf16* attnb = (bf16*)(ws + 75497472);      // 8192*1024*2

    k_cvt<<<8192, 256, 0, stream>>>(x, xb, 2097152);
    k_transpose<<<dim3(96, 32), dim3(32, 8), 0, stream>>>(Wqkv, WqkvT, 1024, 3072);
    k_transpose<<<dim3(32, 32), dim3(32, 8), 0, stream>>>(Wout, WoutT, 1024, 1024);
    k_gemm_bt<0><<<dim3(24, 64), 256, 0, stream>>>(xb, WqkvT, 1024, bqkv, Qg, Kg, Vt, nullptr);
    k_attn<<<2048, 256, 0, stream>>>(Qg, Kg, Vt, attnb);
    k_gemm_bt<1><<<dim3(8, 64), 256, 0, stream>>>(attnb, WoutT, 1024, bout, nullptr, nullptr, nullptr, out);
}

// Round 7
// 447.587 us; speedup vs baseline: 1.3550x; 1.3550x over previous
//
#include <hip/hip_runtime.h>
#include <hip/hip_bf16.h>

typedef __bf16 bf16;
typedef __bf16 bf16x8 __attribute__((ext_vector_type(8)));
typedef __bf16 bf16x4 __attribute__((ext_vector_type(4)));
typedef float f32x4 __attribute__((ext_vector_type(4)));

#define MFMA16(a,b,c) __builtin_amdgcn_mfma_f32_16x16x32_bf16(a,b,c,0,0,0)

// ---------------- convert x (fp32 -> bf16) ----------------
__global__ void k_cvt(const float* __restrict__ in, bf16* __restrict__ out, int n4) {
    int i = blockIdx.x * 256 + threadIdx.x;
    if (i < n4) {
        float4 v = ((const float4*)in)[i];
        bf16x4 o = { (bf16)v.x, (bf16)v.y, (bf16)v.z, (bf16)v.w };
        *(bf16x4*)(out + (long)i * 4) = o;
    }
}

// ---------------- transpose fp32 [R][C] -> bf16 [C][R] ----------------
__global__ void k_transpose(const float* __restrict__ in, bf16* __restrict__ out, int R, int C) {
    __shared__ float t[32][33];
    int c0 = blockIdx.x * 32, r0 = blockIdx.y * 32;
    int tx = threadIdx.x, ty = threadIdx.y; // 32 x 8
    for (int j = 0; j < 4; ++j)
        t[ty + 8 * j][tx] = in[(long)(r0 + ty + 8 * j) * C + c0 + tx];
    __syncthreads();
    for (int j = 0; j < 4; ++j)
        out[(long)(c0 + ty + 8 * j) * R + r0 + tx] = (bf16)t[tx][ty + 8 * j];
}

// ---------------- GEMM C = A * B^T (round-1-identical) ----------------
template <int MODE>
__launch_bounds__(256)
__global__ void k_gemm_bt(const bf16* __restrict__ A, const bf16* __restrict__ BT, int K,
                          const float* __restrict__ bias,
                          bf16* __restrict__ Qg, bf16* __restrict__ Kg, bf16* __restrict__ Vt,
                          float* __restrict__ Out) {
    __shared__ bf16 As[128][40];
    __shared__ bf16 Bs[128][40];
    int tid = threadIdx.x;
    int w = tid >> 6, lane = tid & 63;
    int m0 = blockIdx.y * 128, n0 = blockIdx.x * 128;
    int wm = (w >> 1) * 64, wn = (w & 1) * 64;
    f32x4 acc[4][4] = {};
    int srow = tid >> 1, scol = (tid & 1) * 16;
    const bf16* ap = A + (long)(m0 + srow) * K + scol;
    const bf16* bp = BT + (long)(n0 + srow) * K + scol;
    int la = lane & 15, g8 = (lane >> 4) * 8;

    for (int kk = 0; kk < K; kk += 32) {
        bf16x8 av0 = *(const bf16x8*)(ap + kk);
        bf16x8 av1 = *(const bf16x8*)(ap + kk + 8);
        bf16x8 bv0 = *(const bf16x8*)(bp + kk);
        bf16x8 bv1 = *(const bf16x8*)(bp + kk + 8);
        *(bf16x8*)&As[srow][scol] = av0;
        *(bf16x8*)&As[srow][scol + 8] = av1;
        *(bf16x8*)&Bs[srow][scol] = bv0;
        *(bf16x8*)&Bs[srow][scol + 8] = bv1;
        __syncthreads();
        bf16x8 af[4], bfv[4];
        for (int i = 0; i < 4; ++i) af[i] = *(const bf16x8*)&As[wm + i * 16 + la][g8];
        for (int i = 0; i < 4; ++i) bfv[i] = *(const bf16x8*)&Bs[wn + i * 16 + la][g8];
        for (int i = 0; i < 4; ++i)
            for (int j = 0; j < 4; ++j)
                acc[i][j] = MFMA16(af[i], bfv[j], acc[i][j]);
        __syncthreads();
    }

    for (int j = 0; j < 4; ++j) {
        int n = n0 + wn + j * 16 + la;
        float bb = bias[n];
        if (MODE == 0) {
            int which = n >> 10, e = n & 1023, h = e >> 6, d = e & 63;
            for (int i = 0; i < 4; ++i) {
                int mbase = m0 + wm + i * 16 + (lane >> 4) * 4;
                for (int r = 0; r < 4; ++r) {
                    int m = mbase + r;
                    float v = acc[i][j][r] + bb;
                    int b = m >> 12, s = m & 4095;
                    long bhh = (long)(b * 16 + h);
                    if (which == 0)      Qg[(bhh * 4096 + s) * 64 + d] = (bf16)(v * 0.125f);
                    else if (which == 1) Kg[(bhh * 4096 + s) * 64 + d] = (bf16)v;
                    else                 Vt[(bhh * 64 + d) * 4096 + s] = (bf16)v;
                }
            }
        } else {
            for (int i = 0; i < 4; ++i) {
                int mbase = m0 + wm + i * 16 + (lane >> 4) * 4;
                for (int r = 0; r < 4; ++r)
                    Out[(long)(mbase + r) * 1024 + n] = acc[i][j][r] + bb;
            }
        }
    }
}

// ---------------- flash attention: round-1 structure + layout-safe optimizations ----------------
// All MFMA fragments/layouts identical to the round-1 kernel (hardware-validated).
// New (layout-independent): XOR-swizzled K/V LDS, T14 double-buffer (1 barrier/tile),
// group-max softmax (4 shfl/tile), denominator l = P*ones via MFMA (lane-local divide),
// XCD-aware block swizzle.
__launch_bounds__(256, 3)
__global__ void k_attn(const bf16* __restrict__ Qg, const bf16* __restrict__ Kg,
                       const bf16* __restrict__ Vt, bf16* __restrict__ Ob) {
    __shared__ __align__(16) char lds[32768];   // [2 bufs][K 8KB | V 8KB]
    __shared__ __align__(16) bf16 Pl[4][16][72];
    int wg = blockIdx.x;
    int swz = (wg & 7) * 256 + (wg >> 3);       // bijective: 2048 = 8*256
    int bh = swz >> 6, qt = swz & 63;
    int tid = threadIdx.x, w = tid >> 6, lane = tid & 63;
    int la16 = lane & 15, g4 = lane >> 4, g8 = g4 * 8;

    const bf16* Kbase = Kg + (long)bh * 4096 * 64;
    const bf16* Vbase = Vt + (long)bh * 64 * 4096;
    const bf16* Qp = Qg + ((long)bh * 4096 + qt * 64 + w * 16 + la16) * 64;
    bf16x8 qf0 = *(const bf16x8*)(Qp + g8);        // A[q=la16][d=g8+j]
    bf16x8 qf1 = *(const bf16x8*)(Qp + 32 + g8);   // A[q=la16][d=32+g8+j]

    // staging: thread -> (row = tid>>3 in 0..31, chunk = tid&7); rows row and row+32
    int srow = tid >> 3, sc = tid & 7;
    const bf16* kS = Kbase + (long)srow * 64 + sc * 8;
    const bf16* vS = Vbase + (long)srow * 4096 + sc * 8;
    int sdst = srow * 128 + ((sc ^ (srow & 7)) << 4);   // same xor for row+32

    int x7 = la16 & 7;
    int cA = (g4 ^ x7) << 4;         // chunk g4   (k or kv = g8..g8+7)
    int cB = ((4 + g4) ^ x7) << 4;   // chunk 4+g4 (k or kv = 32+g8..)

    const bf16 one = (bf16)1.0f;
    bf16x8 ones = { one, one, one, one, one, one, one, one };

    f32x4 o[4] = {};
    f32x4 ls = {};
    float mrun = -1e30f;
    const float L2E = 1.44269504f;

    // prologue: stage tile 0 into buf 0
    {
        bf16x8 a  = *(const bf16x8*)(kS);
        bf16x8 b2 = *(const bf16x8*)(kS + 2048);       // +32 kv rows
        bf16x8 c  = *(const bf16x8*)(vS);
        bf16x8 d  = *(const bf16x8*)(vS + 131072);     // +32 d rows
        *(bf16x8*)(lds + sdst) = a;
        *(bf16x8*)(lds + sdst + 4096) = b2;
        *(bf16x8*)(lds + 8192 + sdst) = c;
        *(bf16x8*)(lds + 8192 + sdst + 4096) = d;
    }
    __syncthreads();

    int cur = 0;
    for (int kv0 = 0; kv0 < 4096; kv0 += 64) {
        // T14: issue next tile's global loads before compute
        bf16x8 k0s, k1s, v0s, v1s;
        bool more = (kv0 + 64) < 4096;
        if (more) {
            const bf16* kp = kS + (long)(kv0 + 64) * 64;
            const bf16* vp = vS + (kv0 + 64);
            k0s = *(const bf16x8*)(kp);
            k1s = *(const bf16x8*)(kp + 2048);
            v0s = *(const bf16x8*)(vp);
            v1s = *(const bf16x8*)(vp + 131072);
        }
        const char* kb = lds + cur * 16384;
        const char* vbp = kb + 8192;

        // QK^T (round-1 fragments): s[n] C/D: row q = g4*4+r, col kv = n*16+la16
        f32x4 s[4] = {};
        #pragma unroll
        for (int n = 0; n < 4; ++n) {
            int row = (n * 16 + la16) * 128;
            bf16x8 k0 = *(const bf16x8*)(kb + row + cA);
            bf16x8 k1 = *(const bf16x8*)(kb + row + cB);
            s[n] = MFMA16(qf0, k0, s[n]);
            s[n] = MFMA16(qf1, k1, s[n]);
        }

        // group max over 4 q-rows (g4 group) x 64 kv: 15 fmax + 4 shfl
        float pmax = fmaxf(fmaxf(fmaxf(fmaxf(s[0][0], s[0][1]), fmaxf(s[0][2], s[0][3])),
                                 fmaxf(fmaxf(s[1][0], s[1][1]), fmaxf(s[1][2], s[1][3]))),
                           fmaxf(fmaxf(fmaxf(s[2][0], s[2][1]), fmaxf(s[2][2], s[2][3])),
                                 fmaxf(fmaxf(s[3][0], s[3][1]), fmaxf(s[3][2], s[3][3]))));
        pmax = fmaxf(pmax, __shfl_xor(pmax, 1));
        pmax = fmaxf(pmax, __shfl_xor(pmax, 2));
        pmax = fmaxf(pmax, __shfl_xor(pmax, 4));
        pmax = fmaxf(pmax, __shfl_xor(pmax, 8));
        float nm = fmaxf(mrun, pmax);
        float resc = __builtin_exp2f((mrun - nm) * L2E);
        mrun = nm;
        ls *= resc;
        #pragma unroll
        for (int d = 0; d < 4; ++d) o[d] *= resc;

        // P = exp(S - m), write to per-wave Pl (round-1 path)
        float mL = nm * L2E;
        #pragma unroll
        for (int n = 0; n < 4; ++n)
            #pragma unroll
            for (int r = 0; r < 4; ++r)
                Pl[w][g4 * 4 + r][n * 16 + la16] = (bf16)__builtin_exp2f(s[n][r] * L2E - mL);

        bf16x8 pf0 = *(const bf16x8*)&Pl[w][la16][g8];        // A[q=la16][kv=g8+j]
        bf16x8 pf1 = *(const bf16x8*)&Pl[w][la16][32 + g8];   // A[q=la16][kv=32+g8+j]

        // denominator: ls += P * ones (same bf16 P as PV -> consistent divide)
        ls = MFMA16(pf0, ones, ls);
        ls = MFMA16(pf1, ones, ls);

        // PV (round-1 fragments)
        #pragma unroll
        for (int dblk = 0; dblk < 4; ++dblk) {
            int row = (dblk * 16 + la16) * 128;
            bf16x8 v0 = *(const bf16x8*)(vbp + row + cA);
            bf16x8 v1 = *(const bf16x8*)(vbp + row + cB);
            o[dblk] = MFMA16(pf0, v0, o[dblk]);
            o[dblk] = MFMA16(pf1, v1, o[dblk]);
        }

        if (more) {  // write-late half of T14
            char* dbuf = lds + (cur ^ 1) * 16384;
            *(bf16x8*)(dbuf + sdst) = k0s;
            *(bf16x8*)(dbuf + sdst + 4096) = k1s;
            *(bf16x8*)(dbuf + 8192 + sdst) = v0s;
            *(bf16x8*)(dbuf + 8192 + sdst + 4096) = v1s;
        }
        __syncthreads();
        cur ^= 1;
    }

    // epilogue (round-1 mapping), lane-local divide by ls
    int b = bh >> 4, h = bh & 15;
    long srowq = (long)qt * 64 + w * 16 + g4 * 4;
    #pragma unroll
    for (int dblk = 0; dblk < 4; ++dblk)
        #pragma unroll
        for (int r = 0; r < 4; ++r)
            Ob[((long)b * 4096 + srowq + r) * 1024 + h * 64 + dblk * 16 + la16] =
                (bf16)(o[dblk][r] / ls[r]);
}

extern "C" void kernel_launch(void* const* d_in, const int* in_sizes, int n_in,
                              void* d_out, int out_size, void* d_ws, size_t ws_size,
                              hipStream_t stream) {
    const float* x    = (const float*)d_in[0];
    const float* Wqkv = (const float*)d_in[1];
    const float* bqkv = (const float*)d_in[2];
    const float* Wout = (const float*)d_in[3];
    const float* bout = (const float*)d_in[4];
    float* out = (float*)d_out;
    char* ws = (char*)d_ws;

    bf16* xb    = (bf16*)(ws);                 // 16 MB
    bf16* WqkvT = (bf16*)(ws + 16777216);      // 6 MB
    bf16* WoutT = (bf16*)(ws + 23068672);      // 2 MB
    bf16* Qg    = (bf16*)(ws + 25165824);      // 16 MB
    bf16* Kg    = (bf16*)(ws + 41943040);
    bf16* Vt    = (bf16*)(ws + 58720256);
    bf16* attnb = (bf16*)(ws + 75497472);      // 16 MB

    k_cvt<<<8192, 256, 0, stream>>>(x, xb, 2097152);
    k_transpose<<<dim3(96, 32), dim3(32, 8), 0, stream>>>(Wqkv, WqkvT, 1024, 3072);
    k_transpose<<<dim3(32, 32), dim3(32, 8), 0, stream>>>(Wout, WoutT, 1024, 1024);
    k_gemm_bt<0><<<dim3(24, 64), 256, 0, stream>>>(xb, WqkvT, 1024, bqkv, Qg, Kg, Vt, nullptr);
    k_attn<<<2048, 256, 0, stream>>>(Qg, Kg, Vt, attnb);
    k_gemm_bt<1><<<dim3(8, 64), 256, 0, stream>>>(attnb, WoutT, 1024, bout, nullptr, nullptr, nullptr, out);
}

// Round 8
// 419.246 us; speedup vs baseline: 1.4466x; 1.0676x over previous
//
#include <hip/hip_runtime.h>
#include <hip/hip_bf16.h>

typedef __bf16 bf16;
typedef __bf16 bf16x8 __attribute__((ext_vector_type(8)));
typedef __bf16 bf16x4 __attribute__((ext_vector_type(4)));
typedef float f32x4 __attribute__((ext_vector_type(4)));

#define MFMA16(a,b,c) __builtin_amdgcn_mfma_f32_16x16x32_bf16(a,b,c,0,0,0)

// ---------------- convert x (fp32 -> bf16) ----------------
__global__ void k_cvt(const float* __restrict__ in, bf16* __restrict__ out, int n4) {
    int i = blockIdx.x * 256 + threadIdx.x;
    if (i < n4) {
        float4 v = ((const float4*)in)[i];
        bf16x4 o = { (bf16)v.x, (bf16)v.y, (bf16)v.z, (bf16)v.w };
        *(bf16x4*)(out + (long)i * 4) = o;
    }
}

// ---------------- transpose fp32 [R][C] -> bf16 [C][R] ----------------
__global__ void k_transpose(const float* __restrict__ in, bf16* __restrict__ out, int R, int C) {
    __shared__ float t[32][33];
    int c0 = blockIdx.x * 32, r0 = blockIdx.y * 32;
    int tx = threadIdx.x, ty = threadIdx.y; // 32 x 8
    for (int j = 0; j < 4; ++j)
        t[ty + 8 * j][tx] = in[(long)(r0 + ty + 8 * j) * C + c0 + tx];
    __syncthreads();
    for (int j = 0; j < 4; ++j)
        out[(long)(c0 + ty + 8 * j) * R + r0 + tx] = (bf16)t[tx][ty + 8 * j];
}

// ---------------- GEMM C = A * B^T (round-1-identical) ----------------
template <int MODE>
__launch_bounds__(256)
__global__ void k_gemm_bt(const bf16* __restrict__ A, const bf16* __restrict__ BT, int K,
                          const float* __restrict__ bias,
                          bf16* __restrict__ Qg, bf16* __restrict__ Kg, bf16* __restrict__ Vt,
                          float* __restrict__ Out) {
    __shared__ bf16 As[128][40];
    __shared__ bf16 Bs[128][40];
    int tid = threadIdx.x;
    int w = tid >> 6, lane = tid & 63;
    int m0 = blockIdx.y * 128, n0 = blockIdx.x * 128;
    int wm = (w >> 1) * 64, wn = (w & 1) * 64;
    f32x4 acc[4][4] = {};
    int srow = tid >> 1, scol = (tid & 1) * 16;
    const bf16* ap = A + (long)(m0 + srow) * K + scol;
    const bf16* bp = BT + (long)(n0 + srow) * K + scol;
    int la = lane & 15, g8 = (lane >> 4) * 8;

    for (int kk = 0; kk < K; kk += 32) {
        bf16x8 av0 = *(const bf16x8*)(ap + kk);
        bf16x8 av1 = *(const bf16x8*)(ap + kk + 8);
        bf16x8 bv0 = *(const bf16x8*)(bp + kk);
        bf16x8 bv1 = *(const bf16x8*)(bp + kk + 8);
        *(bf16x8*)&As[srow][scol] = av0;
        *(bf16x8*)&As[srow][scol + 8] = av1;
        *(bf16x8*)&Bs[srow][scol] = bv0;
        *(bf16x8*)&Bs[srow][scol + 8] = bv1;
        __syncthreads();
        bf16x8 af[4], bfv[4];
        for (int i = 0; i < 4; ++i) af[i] = *(const bf16x8*)&As[wm + i * 16 + la][g8];
        for (int i = 0; i < 4; ++i) bfv[i] = *(const bf16x8*)&Bs[wn + i * 16 + la][g8];
        for (int i = 0; i < 4; ++i)
            for (int j = 0; j < 4; ++j)
                acc[i][j] = MFMA16(af[i], bfv[j], acc[i][j]);
        __syncthreads();
    }

    for (int j = 0; j < 4; ++j) {
        int n = n0 + wn + j * 16 + la;
        float bb = bias[n];
        if (MODE == 0) {
            int which = n >> 10, e = n & 1023, h = e >> 6, d = e & 63;
            for (int i = 0; i < 4; ++i) {
                int mbase = m0 + wm + i * 16 + (lane >> 4) * 4;
                for (int r = 0; r < 4; ++r) {
                    int m = mbase + r;
                    float v = acc[i][j][r] + bb;
                    int b = m >> 12, s = m & 4095;
                    long bhh = (long)(b * 16 + h);
                    if (which == 0)      Qg[(bhh * 4096 + s) * 64 + d] = (bf16)(v * 0.125f);
                    else if (which == 1) Kg[(bhh * 4096 + s) * 64 + d] = (bf16)v;
                    else                 Vt[(bhh * 64 + d) * 4096 + s] = (bf16)v;
                }
            }
        } else {
            for (int i = 0; i < 4; ++i) {
                int mbase = m0 + wm + i * 16 + (lane >> 4) * 4;
                for (int r = 0; r < 4; ++r)
                    Out[(long)(mbase + r) * 1024 + n] = acc[i][j][r] + bb;
            }
        }
    }
}

// ---------------- flash attention (round-7 structure + occupancy/defer-max deltas) ----------------
// Round-7-validated MFMA fragments throughout. Deltas:
//  (1) Pl -> [16][64] unpadded with chunk-XOR swizzle (LDS 40960 B -> 4 blocks/CU)
//  (2) exact defer-max: skip rescale when no column max grew (bit-exact skip)
//  (3) rcp-based epilogue divide, __launch_bounds__(256,4)
__launch_bounds__(256, 4)
__global__ void k_attn(const bf16* __restrict__ Qg, const bf16* __restrict__ Kg,
                       const bf16* __restrict__ Vt, bf16* __restrict__ Ob) {
    __shared__ __align__(16) char lds[32768];   // [2 bufs][K 8KB | V 8KB]
    __shared__ __align__(16) bf16 Pl[4][16][64];
    int wg = blockIdx.x;
    int swz = (wg & 7) * 256 + (wg >> 3);       // bijective: 2048 = 8*256
    int bh = swz >> 6, qt = swz & 63;
    int tid = threadIdx.x, w = tid >> 6, lane = tid & 63;
    int la16 = lane & 15, g4 = lane >> 4, g8 = g4 * 8;

    const bf16* Kbase = Kg + (long)bh * 4096 * 64;
    const bf16* Vbase = Vt + (long)bh * 64 * 4096;
    const bf16* Qp = Qg + ((long)bh * 4096 + qt * 64 + w * 16 + la16) * 64;
    bf16x8 qf0 = *(const bf16x8*)(Qp + g8);        // A[q=la16][d=g8+j]
    bf16x8 qf1 = *(const bf16x8*)(Qp + 32 + g8);   // A[q=la16][d=32+g8+j]

    // staging: thread -> (row = tid>>3 in 0..31, chunk = tid&7); rows row and row+32
    int srow = tid >> 3, sc = tid & 7;
    const bf16* kS = Kbase + (long)srow * 64 + sc * 8;
    const bf16* vS = Vbase + (long)srow * 4096 + sc * 8;
    int sdst = srow * 128 + ((sc ^ (srow & 7)) << 4);   // same xor for row+32

    int x7 = la16 & 7;
    int cA = (g4 ^ x7) << 4;         // chunk g4   (k or kv = g8..g8+7)
    int cB = ((4 + g4) ^ x7) << 4;   // chunk 4+g4 (k or kv = 32+g8..)

    const bf16 one = (bf16)1.0f;
    bf16x8 ones = { one, one, one, one, one, one, one, one };

    // Pl swizzle: element [row][col] stored at col' = ((col>>3) ^ (row&7))*8 + (col&7)
    bf16* pwr = &Pl[w][0][0];
    int prd0 = la16 * 64 + ((g4 ^ x7) << 3);         // read chunk g4 of row la16
    int prd1 = la16 * 64 + (((4 + g4) ^ x7) << 3);   // read chunk 4+g4

    f32x4 o[4] = {};
    f32x4 ls = {};
    float mrun = -1e30f;
    const float L2E = 1.44269504f;

    // prologue: stage tile 0 into buf 0
    {
        bf16x8 a  = *(const bf16x8*)(kS);
        bf16x8 b2 = *(const bf16x8*)(kS + 2048);       // +32 kv rows
        bf16x8 c  = *(const bf16x8*)(vS);
        bf16x8 d  = *(const bf16x8*)(vS + 131072);     // +32 d rows
        *(bf16x8*)(lds + sdst) = a;
        *(bf16x8*)(lds + sdst + 4096) = b2;
        *(bf16x8*)(lds + 8192 + sdst) = c;
        *(bf16x8*)(lds + 8192 + sdst + 4096) = d;
    }
    __syncthreads();

    int cur = 0;
    for (int kv0 = 0; kv0 < 4096; kv0 += 64) {
        // T14: issue next tile's global loads before compute
        bf16x8 k0s, k1s, v0s, v1s;
        bool more = (kv0 + 64) < 4096;
        if (more) {
            const bf16* kp = kS + (long)(kv0 + 64) * 64;
            const bf16* vp = vS + (kv0 + 64);
            k0s = *(const bf16x8*)(kp);
            k1s = *(const bf16x8*)(kp + 2048);
            v0s = *(const bf16x8*)(vp);
            v1s = *(const bf16x8*)(vp + 131072);
        }
        const char* kb = lds + cur * 16384;
        const char* vbp = kb + 8192;

        // QK^T (round-1 fragments): s[n] C/D: row q = g4*4+r, col kv = n*16+la16
        f32x4 s[4] = {};
        #pragma unroll
        for (int n = 0; n < 4; ++n) {
            int row = (n * 16 + la16) * 128;
            bf16x8 k0 = *(const bf16x8*)(kb + row + cA);
            bf16x8 k1 = *(const bf16x8*)(kb + row + cB);
            s[n] = MFMA16(qf0, k0, s[n]);
            s[n] = MFMA16(qf1, k1, s[n]);
        }

        // group max over 4 q-rows (g4 group) x 64 kv: 15 fmax + 4 shfl
        float pmax = fmaxf(fmaxf(fmaxf(fmaxf(s[0][0], s[0][1]), fmaxf(s[0][2], s[0][3])),
                                 fmaxf(fmaxf(s[1][0], s[1][1]), fmaxf(s[1][2], s[1][3]))),
                           fmaxf(fmaxf(fmaxf(s[2][0], s[2][1]), fmaxf(s[2][2], s[2][3])),
                                 fmaxf(fmaxf(s[3][0], s[3][1]), fmaxf(s[3][2], s[3][3]))));
        pmax = fmaxf(pmax, __shfl_xor(pmax, 1));
        pmax = fmaxf(pmax, __shfl_xor(pmax, 2));
        pmax = fmaxf(pmax, __shfl_xor(pmax, 4));
        pmax = fmaxf(pmax, __shfl_xor(pmax, 8));
        // exact defer-max: if no column grew, rescale would be exp2(0)=1 -> skip is bit-exact
        if (__any(pmax > mrun)) {
            float nm = fmaxf(mrun, pmax);
            float resc = __builtin_exp2f((mrun - nm) * L2E);
            mrun = nm;
            ls *= resc;
            #pragma unroll
            for (int d = 0; d < 4; ++d) o[d] *= resc;
        }

        // P = exp(S - m), write to swizzled per-wave Pl
        float mL = mrun * L2E;
        #pragma unroll
        for (int n = 0; n < 4; ++n) {
            #pragma unroll
            for (int r = 0; r < 4; ++r) {
                int row = g4 * 4 + r;
                int csw = (((2 * n + (la16 >> 3)) ^ (row & 7)) << 3) + (la16 & 7);
                pwr[row * 64 + csw] = (bf16)__builtin_exp2f(s[n][r] * L2E - mL);
            }
        }

        bf16x8 pf0 = *(const bf16x8*)(pwr + prd0);   // A[q=la16][kv=g8+j]
        bf16x8 pf1 = *(const bf16x8*)(pwr + prd1);   // A[q=la16][kv=32+g8+j]

        // denominator: ls += P * ones (same bf16 P as PV -> consistent divide)
        ls = MFMA16(pf0, ones, ls);
        ls = MFMA16(pf1, ones, ls);

        // PV (round-1 fragments)
        #pragma unroll
        for (int dblk = 0; dblk < 4; ++dblk) {
            int row = (dblk * 16 + la16) * 128;
            bf16x8 v0 = *(const bf16x8*)(vbp + row + cA);
            bf16x8 v1 = *(const bf16x8*)(vbp + row + cB);
            o[dblk] = MFMA16(pf0, v0, o[dblk]);
            o[dblk] = MFMA16(pf1, v1, o[dblk]);
        }

        if (more) {  // write-late half of T14
            char* dbuf = lds + (cur ^ 1) * 16384;
            *(bf16x8*)(dbuf + sdst) = k0s;
            *(bf16x8*)(dbuf + sdst + 4096) = k1s;
            *(bf16x8*)(dbuf + 8192 + sdst) = v0s;
            *(bf16x8*)(dbuf + 8192 + sdst + 4096) = v1s;
        }
        __syncthreads();
        cur ^= 1;
    }

    // epilogue (round-1 mapping), rcp divide (bf16 output precision)
    f32x4 linv;
    #pragma unroll
    for (int r = 0; r < 4; ++r) linv[r] = __builtin_amdgcn_rcpf(ls[r]);
    int b = bh >> 4, h = bh & 15;
    long srowq = (long)qt * 64 + w * 16 + g4 * 4;
    #pragma unroll
    for (int dblk = 0; dblk < 4; ++dblk)
        #pragma unroll
        for (int r = 0; r < 4; ++r)
            Ob[((long)b * 4096 + srowq + r) * 1024 + h * 64 + dblk * 16 + la16] =
                (bf16)(o[dblk][r] * linv[r]);
}

extern "C" void kernel_launch(void* const* d_in, const int* in_sizes, int n_in,
                              void* d_out, int out_size, void* d_ws, size_t ws_size,
                              hipStream_t stream) {
    const float* x    = (const float*)d_in[0];
    const float* Wqkv = (const float*)d_in[1];
    const float* bqkv = (const float*)d_in[2];
    const float* Wout = (const float*)d_in[3];
    const float* bout = (const float*)d_in[4];
    float* out = (float*)d_out;
    char* ws = (char*)d_ws;

    bf16* xb    = (bf16*)(ws);                 // 16 MB
    bf16* WqkvT = (bf16*)(ws + 16777216);      // 6 MB
    bf16* WoutT = (bf16*)(ws + 23068672);      // 2 MB
    bf16* Qg    = (bf16*)(ws + 25165824);      // 16 MB
    bf16* Kg    = (bf16*)(ws + 41943040);
    bf16* Vt    = (bf16*)(ws + 58720256);
    bf16* attnb = (bf16*)(ws + 75497472);      // 16 MB

    k_cvt<<<8192, 256, 0, stream>>>(x, xb, 2097152);
    k_transpose<<<dim3(96, 32), dim3(32, 8), 0, stream>>>(Wqkv, WqkvT, 1024, 3072);
    k_transpose<<<dim3(32, 32), dim3(32, 8), 0, stream>>>(Wout, WoutT, 1024, 1024);
    k_gemm_bt<0><<<dim3(24, 64), 256, 0, stream>>>(xb, WqkvT, 1024, bqkv, Qg, Kg, Vt, nullptr);
    k_attn<<<2048, 256, 0, stream>>>(Qg, Kg, Vt, attnb);
    k_gemm_bt<1><<<dim3(8, 64), 256, 0, stream>>>(attnb, WoutT, 1024, bout, nullptr, nullptr, nullptr, out);
}